// Round 10
// baseline (153.529 us; speedup 1.0000x reference)
//
#include <hip/hip_runtime.h>
#include <hip/hip_fp16.h>

#define B_    64
#define H_    448
#define W_    448
#define OUT_  256
#define HB_   486
#define WB_   486
#define HW_   (H_*W_)        // 200704
#define OO_   (OUT_*OUT_)    // 65536
#define F4PP  (HW_/4)        // 50176 float4 per channel plane
#define F4PB  (F4PP/16)      // 3136 float4 per K1 block per plane
#define MBPS  (HW_/8)        // 25088 mask bytes per sample (bit-packed)
#define BMF4S (2*HW_/4)      // 100352 float4 per sample (bm)
#define BMQ   (BMF4S/128)    // 784 float4 per k2 block (128 slots/sample)

__device__ __forceinline__ float clip01(float v) { return fminf(fmaxf(v, 0.f), 1.f); }
__device__ __forceinline__ float pmodf_(float a, float m) {
  float r = fmodf(a, m);
  return (r < 0.f) ? r + m : r;
}

struct Params {
  int minx, miny, maxx, maxy, c0, c2, usebg, Hp, Wp;
  float scX, scY, offx, szx, offy, szy;
};

// uniform per-block param recompute (all addresses uniform -> scalar loads)
__device__ __forceinline__ Params make_params(const int* __restrict__ pb,
                                              const int* __restrict__ cbuf, int s) {
  int mnX = W_, mxX = -1, mnY = H_, mxY = -1;
  #pragma unroll
  for (int t = 0; t < 16; ++t) {
    int base = (s*16 + t) * 4;
    mnX = min(mnX, pb[base+0]); mxX = max(mxX, pb[base+1]);
    mnY = min(mnY, pb[base+2]); mxY = max(mxY, pb[base+3]);
  }
  if (mxY < 0) { mnY = 0; mxY = H_-1; }
  if (mxX < 0) { mnX = 0; mxX = W_-1; }
  int c0 = cbuf[s*5+0], c1 = cbuf[s*5+1], c2 = cbuf[s*5+2],
      c3 = cbuf[s*5+3], c4 = cbuf[s*5+4];
  Params P;
  P.minx = mnX; P.miny = mnY; P.maxx = mxX; P.maxy = mxY;
  P.c0 = c0; P.c2 = c2; P.usebg = (c4 > 2);
  P.Hp = mxY - mnY + 1 + c2 + c3;
  P.Wp = mxX - mnX + 1 + c0 + c1;
  P.scX = (float)P.Wp / (float)OUT_;
  P.scY = (float)P.Hp / (float)OUT_;
  P.offx = (float)(mnX - c0); P.szx = (float)P.Wp;
  P.offy = (float)(mnY - c2); P.szy = (float)P.Hp;
  return P;
}

// ---------------- K1: bit-packed mask + bbox block partials ----------------
__global__ void k1_bboxmask(const float* __restrict__ wc, unsigned char* __restrict__ maskbits,
                            int* __restrict__ pb, int useMask) {
  int blk = blockIdx.x, tid = threadIdx.x;
  int s = blk >> 4, slot = blk & 15;
  const float4* w0 = (const float4*)(wc + (size_t)s*3*HW_);
  const float4* w1 = w0 + F4PP;
  const float4* w2 = w1 + F4PP;
  unsigned char* mbs = maskbits + (size_t)s*MBPS;
  int lane = tid & 63;
  int mnX = W_, mxX = -1, mnY = H_, mxY = -1;
  for (int j = tid; j < F4PB; j += 256) {
    int i = slot*F4PB + j;
    float4 a = w0[i], b = w1[i], c = w2[i];
    int m0 = (a.x != 0.f && b.x != 0.f && c.x != 0.f);
    int m1 = (a.y != 0.f && b.y != 0.f && c.y != 0.f);
    int m2 = (a.z != 0.f && b.z != 0.f && c.z != 0.f);
    int m3 = (a.w != 0.f && b.w != 0.f && c.w != 0.f);
    if (useMask) {
      int nib = m0 | (m1<<1) | (m2<<2) | (m3<<3);
      int nxt = __shfl(nib, lane + 1, 64);
      if ((lane & 1) == 0)
        mbs[i >> 1] = (unsigned char)(nib | (nxt << 4));
    }
    if (m0 | m1 | m2 | m3) {
      int y  = i / 112;
      int x0 = (i - y*112) * 4;
      mnY = min(mnY, y); mxY = max(mxY, y);
      int first = m0 ? 0 : (m1 ? 1 : (m2 ? 2 : 3));
      int last  = m3 ? 3 : (m2 ? 2 : (m1 ? 1 : 0));
      mnX = min(mnX, x0 + first);
      mxX = max(mxX, x0 + last);
    }
  }
  __shared__ int sr[4][256];
  sr[0][tid]=mnX; sr[1][tid]=mxX; sr[2][tid]=mnY; sr[3][tid]=mxY;
  __syncthreads();
  for (int off = 128; off > 0; off >>= 1) {
    if (tid < off) {
      sr[0][tid] = min(sr[0][tid], sr[0][tid+off]);
      sr[1][tid] = max(sr[1][tid], sr[1][tid+off]);
      sr[2][tid] = min(sr[2][tid], sr[2][tid+off]);
      sr[3][tid] = max(sr[3][tid], sr[3][tid+off]);
    }
    __syncthreads();
  }
  if (tid == 0) {
    pb[blk*4+0] = sr[0][0]; pb[blk*4+1] = sr[1][0];
    pb[blk*4+2] = sr[2][0]; pb[blk*4+3] = sr[3][0];
  }
}

// ---------------- K2: compose 2 rows/thread + ballot gating + hidden bm ----------------
__global__ void k2_compose(const float* __restrict__ img, const float* __restrict__ bg,
                           const float* __restrict__ wc, const unsigned char* __restrict__ maskbits,
                           const float* __restrict__ col, const float* __restrict__ bri,
                           const int* __restrict__ pb, const int* __restrict__ cbuf,
                           const float* __restrict__ bm, float* __restrict__ bmout,
                           __half* __restrict__ xh, float* __restrict__ xout,
                           float* __restrict__ gpart, int useMask, int useHalf) {
  int tid = threadIdx.x, blk = blockIdx.x;
  int s = blk >> 7;                 // 128 slots per sample, 2 rows each
  int slot = blk & 127;
  int px = tid;

  // ---- bm stream: issue loads first, consume at the very end ----
  const float4* bm4 = (const float4*)(bm + (size_t)s*2*HW_);
  int jb = slot*BMQ;
  float4 bv0 = bm4[jb + tid];
  float4 bv1 = bm4[jb + tid + 256];
  float4 bv2 = bm4[jb + tid + 512];
  bool h3 = tid < (BMQ - 768);      // tid < 16
  float4 bv3 = h3 ? bm4[jb + tid + 768] : make_float4(0.f,0.f,0.f,0.f);

  Params P = make_params(pb, cbuf, s);
  float colr = col[s*3+0], colg = col[s*3+1], colb = col[s*3+2];
  float brf = bri[s];

  const float* imgb = img + (size_t)s*3*HW_;
  const float* bgb  = bg  + (size_t)s*3*HB_*WB_;
  const float* w0p  = wc  + (size_t)s*3*HW_;
  const unsigned char* mbs = maskbits + (size_t)s*MBPS;

  // ---- x geometry (shared by both rows) ----
  float sx = fmaxf((px + 0.5f) * P.scX - 0.5f, 0.f);
  int   x0 = (int)sx;
  float wx = sx - (float)x0;
  x0 = min(x0, P.Wp - 1);
  int x1 = min(x0 + 1, P.Wp - 1);
  int ox0 = x0 - P.c0 + P.minx, ox1 = x1 - P.c0 + P.minx;
  bool vx0 = (ox0 >= P.minx) && (ox0 <= P.maxx);
  bool vx1 = (ox1 >= P.minx) && (ox1 <= P.maxx);
  int ox0c = min(max(ox0, 0), W_-1), ox1c = min(max(ox1, 0), W_-1);
  int bx0 = min(x0, WB_-1), bx1 = min(x1, WB_-1);

  // ---- y geometry per row ----
  int   yy0[2], yy1[2];
  float wyv[2];
  bool  vy0[2], vy1[2];
  int   oy0c[2], oy1c[2], byy0[2], byy1[2];
  #pragma unroll
  for (int r = 0; r < 2; ++r) {
    int py = slot*2 + r;
    float sy = fmaxf((py + 0.5f) * P.scY - 0.5f, 0.f);
    int   y0 = (int)sy;
    wyv[r] = sy - (float)y0;
    y0 = min(y0, P.Hp - 1);
    int y1 = min(y0 + 1, P.Hp - 1);
    yy0[r] = y0; yy1[r] = y1;
    int oy0 = y0 - P.c2 + P.miny, oy1 = y1 - P.c2 + P.miny;
    vy0[r] = (oy0 >= P.miny) && (oy0 <= P.maxy);
    vy1[r] = (oy1 >= P.miny) && (oy1 <= P.maxy);
    oy0c[r] = min(max(oy0, 0), H_-1);
    oy1c[r] = min(max(oy1, 0), H_-1);
    byy0[r] = min(y0, HB_-1);
    byy1[r] = min(y1, HB_-1);
  }

  // tap indices [r][t]: t = 0:(y0,x0) 1:(y0,x1) 2:(y1,x0) 3:(y1,x1)
  int mi[2][4];
  #pragma unroll
  for (int r = 0; r < 2; ++r) {
    mi[r][0] = oy0c[r]*W_ + ox0c;  mi[r][1] = oy0c[r]*W_ + ox1c;
    mi[r][2] = oy1c[r]*W_ + ox0c;  mi[r][3] = oy1c[r]*W_ + ox1c;
  }

  // ---- masks first (L2-hot), then gate heavy gathers ----
  float m[2][4];
  #pragma unroll
  for (int r = 0; r < 2; ++r) {
    if (useMask) {
      #pragma unroll
      for (int t = 0; t < 4; ++t)
        m[r][t] = (float)((mbs[mi[r][t] >> 3] >> (mi[r][t] & 7)) & 1);
    } else {
      #pragma unroll
      for (int t = 0; t < 4; ++t) {
        int k = mi[r][t];
        m[r][t] = (w0p[k] != 0.f && w0p[k+HW_] != 0.f && w0p[k+2*HW_] != 0.f) ? 1.f : 0.f;
      }
    }
    if (!(vy0[r] && vx0)) m[r][0] = 0.f;
    if (!(vy0[r] && vx1)) m[r][1] = 0.f;
    if (!(vy1[r] && vx0)) m[r][2] = 0.f;
    if (!(vy1[r] && vx1)) m[r][3] = 0.f;
  }
  float msum = 0.f, mprod = 1.f;
  #pragma unroll
  for (int r = 0; r < 2; ++r)
    #pragma unroll
    for (int t = 0; t < 4; ++t) { msum += m[r][t]; mprod *= m[r][t]; }
  bool needImg = __any(msum > 0.f);
  bool needBg  = __any(mprod < 1.f);

  float iv[2][4][3];
  #pragma unroll
  for (int r = 0; r < 2; ++r)
    #pragma unroll
    for (int t = 0; t < 4; ++t)
      { iv[r][t][0]=0.f; iv[r][t][1]=0.f; iv[r][t][2]=0.f; }
  if (needImg) {
    #pragma unroll
    for (int ch = 0; ch < 3; ++ch) {
      size_t o = (size_t)ch*HW_;
      #pragma unroll
      for (int r = 0; r < 2; ++r)
        #pragma unroll
        for (int t = 0; t < 4; ++t)
          iv[r][t][ch] = imgb[o + mi[r][t]];
    }
  }

  float gv[2][4][3];
  if (P.usebg) {
    if (needBg) {
      const size_t PL = (size_t)HB_*WB_;
      size_t bo[2][4];
      #pragma unroll
      for (int r = 0; r < 2; ++r) {
        bo[r][0] = (size_t)byy0[r]*WB_ + bx0;  bo[r][1] = (size_t)byy0[r]*WB_ + bx1;
        bo[r][2] = (size_t)byy1[r]*WB_ + bx0;  bo[r][3] = (size_t)byy1[r]*WB_ + bx1;
      }
      #pragma unroll
      for (int ch = 0; ch < 3; ++ch)
        #pragma unroll
        for (int r = 0; r < 2; ++r)
          #pragma unroll
          for (int t = 0; t < 4; ++t)
            gv[r][t][ch] = bgb[bo[r][t] + ch*PL];
    } else {
      #pragma unroll
      for (int r = 0; r < 2; ++r)
        #pragma unroll
        for (int t = 0; t < 4; ++t)
          { gv[r][t][0]=0.f; gv[r][t][1]=0.f; gv[r][t][2]=0.f; }
    }
  } else {
    #pragma unroll
    for (int r = 0; r < 2; ++r)
      #pragma unroll
      for (int t = 0; t < 4; ++t)
        { gv[r][t][0]=colr; gv[r][t][1]=colg; gv[r][t][2]=colb; }
  }

  // ---- blend + store (fp16) + gray accumulate ----
  float gsum = 0.f;
  #pragma unroll
  for (int r = 0; r < 2; ++r) {
    int p = ((slot*2 + r) << 8) | px;
    float xr[3];
    #pragma unroll
    for (int ch = 0; ch < 3; ++ch) {
      float a00 = iv[r][0][ch]*m[r][0] + gv[r][0][ch]*(1.f-m[r][0]);
      float a01 = iv[r][1][ch]*m[r][1] + gv[r][1][ch]*(1.f-m[r][1]);
      float a10 = iv[r][2][ch]*m[r][2] + gv[r][2][ch]*(1.f-m[r][2]);
      float a11 = iv[r][3][ch]*m[r][3] + gv[r][3][ch]*(1.f-m[r][3]);
      float top = a00*(1.f-wx) + a01*wx;
      float bot = a10*(1.f-wx) + a11*wx;
      float o = top*(1.f-wyv[r]) + bot*wyv[r];
      xr[ch] = clip01(o * brf);
      size_t oi = (size_t)(s*3 + ch)*OO_ + p;
      if (useHalf) xh[oi] = __float2half(xr[ch]);
      else         xout[oi] = xr[ch];
    }
    gsum += 0.299f*xr[0] + 0.587f*xr[1] + 0.114f*xr[2];
  }

  // ---- reduction: wave shuffle + single cross-wave step ----
  #pragma unroll
  for (int off = 32; off > 0; off >>= 1)
    gsum += __shfl_xor(gsum, off, 64);
  __shared__ float swv[4];
  int wv = tid >> 6, lane = tid & 63;
  if (lane == 0) swv[wv] = gsum;
  __syncthreads();
  if (tid == 0) gpart[blk] = swv[0] + swv[1] + swv[2] + swv[3];

  // ---- bm stream: transform + store ----
  {
    float4* out4 = (float4*)(bmout + (size_t)s*2*HW_);
    float invx = 2.f / P.szx, invy = 2.f / P.szy;
    auto emit = [&](int idx, const float4& v) {
      float off_ = (idx < F4PP) ? P.offx : P.offy;
      float inv  = (idx < F4PP) ? invx  : invy;
      float4 o;
      o.x = (v.x - off_) * inv - 1.f;
      o.y = (v.y - off_) * inv - 1.f;
      o.z = (v.z - off_) * inv - 1.f;
      o.w = (v.w - off_) * inv - 1.f;
      out4[idx] = o;
    };
    emit(jb + tid,       bv0);
    emit(jb + tid + 256, bv1);
    emit(jb + tid + 512, bv2);
    if (h3) emit(jb + tid + 768, bv3);
  }
}

// ---------------- KB: mean + contrast/saturation/hue, 4 px/thread ----------------
__global__ void kb_color(const __half* __restrict__ xh, const float* __restrict__ gpart,
                         const float* __restrict__ con, const float* __restrict__ sat,
                         const float* __restrict__ hue, float* __restrict__ xout,
                         int useHalf) {
  int tid = threadIdx.x, blk = blockIdx.x;
  int s = blk >> 6, slot = blk & 63;
  int u = slot*256 + tid;           // 4-px unit within plane [0, 16384)

  float sum = 0.f;
  for (int t = 0; t < 128; ++t) sum += gpart[s*128 + t];
  float mean = sum * (1.f / (float)OO_);
  float cf = con[s], sfc = sat[s], hu = hue[s];

  float in[3][4];
  #pragma unroll
  for (int ch = 0; ch < 3; ++ch) {
    size_t base = (size_t)(s*3 + ch)*OO_ + (size_t)u*4;
    if (useHalf) {
      uint2 q = ((const uint2*)xh)[base >> 2];
      __half2 h01 = *(__half2*)&q.x;
      __half2 h23 = *(__half2*)&q.y;
      float2 f01 = __half22float2(h01);
      float2 f23 = __half22float2(h23);
      in[ch][0]=f01.x; in[ch][1]=f01.y; in[ch][2]=f23.x; in[ch][3]=f23.y;
    } else {
      float4 f = ((const float4*)xout)[base >> 2];
      in[ch][0]=f.x; in[ch][1]=f.y; in[ch][2]=f.z; in[ch][3]=f.w;
    }
  }

  float ro[4], go[4], bo[4];
  #pragma unroll
  for (int l = 0; l < 4; ++l) {
    float r = in[0][l], g = in[1][l], bl = in[2][l];
    r  = clip01(cf*r  + (1.f-cf)*mean);
    g  = clip01(cf*g  + (1.f-cf)*mean);
    bl = clip01(cf*bl + (1.f-cf)*mean);

    float gr = 0.299f*r + 0.587f*g + 0.114f*bl;
    r  = clip01(sfc*r  + (1.f-sfc)*gr);
    g  = clip01(sfc*g  + (1.f-sfc)*gr);
    bl = clip01(sfc*bl + (1.f-sfc)*gr);

    const float eps = 1e-8f;
    float mx = fmaxf(r, fmaxf(g, bl));
    float mn = fminf(r, fminf(g, bl));
    float d  = mx - mn;
    float inv = 1.f / (d + eps);
    float h;
    if (mx == r)      h = pmodf_((g - bl) * inv, 6.f);
    else if (mx == g) h = (bl - r) * inv + 2.f;
    else              h = (r - g) * inv + 4.f;
    h *= (1.f/6.f);
    if (d <= eps) h = 0.f;
    float sv = d / (mx + eps);
    float v  = mx;

    h = pmodf_(h + hu, 1.f);

    float h6 = pmodf_(h, 1.f) * 6.f;
    float fi = floorf(h6);
    float f  = h6 - fi;
    int   i6 = ((int)fi) % 6;
    float pp = v * (1.f - sv);
    float q  = v * (1.f - f*sv);
    float t  = v * (1.f - (1.f - f)*sv);
    float rr, gg, bb;
    switch (i6) {
      case 0:  rr=v;  gg=t;  bb=pp; break;
      case 1:  rr=q;  gg=v;  bb=pp; break;
      case 2:  rr=pp; gg=v;  bb=t;  break;
      case 3:  rr=pp; gg=q;  bb=v;  break;
      case 4:  rr=t;  gg=pp; bb=v;  break;
      default: rr=v;  gg=pp; bb=q;  break;
    }
    ro[l] = clip01(rr); go[l] = clip01(gg); bo[l] = clip01(bb);
  }
  size_t ub = (size_t)(s*3)*OO_ + (size_t)u*4;
  ((float4*)xout)[(ub)                 >> 2] = make_float4(ro[0],ro[1],ro[2],ro[3]);
  ((float4*)xout)[(ub +   (size_t)OO_) >> 2] = make_float4(go[0],go[1],go[2],go[3]);
  ((float4*)xout)[(ub + 2*(size_t)OO_) >> 2] = make_float4(bo[0],bo[1],bo[2],bo[3]);
}

extern "C" void kernel_launch(void* const* d_in, const int* in_sizes, int n_in,
                              void* d_out, int out_size, void* d_ws, size_t ws_size,
                              hipStream_t stream) {
  const float* img = (const float*)d_in[0];
  const float* wc  = (const float*)d_in[1];
  const float* bm  = (const float*)d_in[2];
  const float* bg  = (const float*)d_in[3];
  const float* col = (const float*)d_in[4];
  const float* bri = (const float*)d_in[5];
  const float* con = (const float*)d_in[6];
  const float* sat = (const float*)d_in[7];
  const float* hue = (const float*)d_in[8];
  const int*   cb  = (const int*)d_in[9];

  float* outx  = (float*)d_out;
  float* outbm = outx + (size_t)B_*3*OO_;

  char* ws = (char*)d_ws;
  int*   pb    = (int*)ws;                                  // [0, 16384)
  float* gpart = (float*)(ws + 16384);                      // 8192 * 4B = 32768
  unsigned char* maskbits = (unsigned char*)(ws + 81920);   // 1,605,632 B
  __half* xh = (__half*)(ws + 1687552);                     // 25,165,824 B

  size_t needMask = 81920 + (size_t)B_*MBPS;                // ~1.69 MB
  size_t needHalf = 1687552 + (size_t)B_*3*OO_*2;           // ~26.9 MB
  int useMask = (ws_size >= needMask) ? 1 : 0;
  int useHalf = (ws_size >= needHalf) ? 1 : 0;

  k1_bboxmask<<<1024, 256, 0, stream>>>(wc, maskbits, pb, useMask);
  k2_compose <<<8192, 256, 0, stream>>>(img, bg, wc, maskbits, col, bri, pb, cb,
                                        bm, outbm, xh, outx, gpart,
                                        useMask, useHalf);
  kb_color   <<<4096, 256, 0, stream>>>(xh, gpart, con, sat, hue, outx, useHalf);
}

// Round 11
// 144.935 us; speedup vs baseline: 1.0593x; 1.0593x over previous
//
#include <hip/hip_runtime.h>
#include <hip/hip_fp16.h>

#define B_    64
#define H_    448
#define W_    448
#define OUT_  256
#define HB_   486
#define WB_   486
#define HW_   (H_*W_)        // 200704
#define OO_   (OUT_*OUT_)    // 65536
#define F4PP  (HW_/4)        // 50176 float4 per channel plane
#define F4PB  (F4PP/16)      // 3136 float4 per K1 block per plane
#define MBPS  (HW_/8)        // 25088 mask bytes per sample (bit-packed)
#define BMF4S (2*HW_/4)      // 100352 float4 per sample (bm)
#define BM4PB (BMF4S/256)    // 392 float4 per k2 block

typedef float fx4 __attribute__((ext_vector_type(4)));

__device__ __forceinline__ float clip01(float v) { return fminf(fmaxf(v, 0.f), 1.f); }
__device__ __forceinline__ float pmodf_(float a, float m) {
  float r = fmodf(a, m);
  return (r < 0.f) ? r + m : r;
}

struct Params {
  int minx, miny, maxx, maxy, c0, c2, usebg, Hp, Wp;
  float scX, scY, offx, szx, offy, szy;
};

// uniform per-block param recompute (all addresses uniform -> scalar loads)
__device__ __forceinline__ Params make_params(const int* __restrict__ pb,
                                              const int* __restrict__ cbuf, int s) {
  int mnX = W_, mxX = -1, mnY = H_, mxY = -1;
  #pragma unroll
  for (int t = 0; t < 16; ++t) {
    int base = (s*16 + t) * 4;
    mnX = min(mnX, pb[base+0]); mxX = max(mxX, pb[base+1]);
    mnY = min(mnY, pb[base+2]); mxY = max(mxY, pb[base+3]);
  }
  if (mxY < 0) { mnY = 0; mxY = H_-1; }
  if (mxX < 0) { mnX = 0; mxX = W_-1; }
  int c0 = cbuf[s*5+0], c1 = cbuf[s*5+1], c2 = cbuf[s*5+2],
      c3 = cbuf[s*5+3], c4 = cbuf[s*5+4];
  Params P;
  P.minx = mnX; P.miny = mnY; P.maxx = mxX; P.maxy = mxY;
  P.c0 = c0; P.c2 = c2; P.usebg = (c4 > 2);
  P.Hp = mxY - mnY + 1 + c2 + c3;
  P.Wp = mxX - mnX + 1 + c0 + c1;
  P.scX = (float)P.Wp / (float)OUT_;
  P.scY = (float)P.Hp / (float)OUT_;
  P.offx = (float)(mnX - c0); P.szx = (float)P.Wp;
  P.offy = (float)(mnY - c2); P.szy = (float)P.Hp;
  return P;
}

// ---------------- K1: bit-packed mask + bbox block partials ----------------
__global__ void k1_bboxmask(const float* __restrict__ wc, unsigned char* __restrict__ maskbits,
                            int* __restrict__ pb, int useMask) {
  int blk = blockIdx.x, tid = threadIdx.x;
  int s = blk >> 4, slot = blk & 15;
  const float4* w0 = (const float4*)(wc + (size_t)s*3*HW_);
  const float4* w1 = w0 + F4PP;
  const float4* w2 = w1 + F4PP;
  unsigned char* mbs = maskbits + (size_t)s*MBPS;
  int lane = tid & 63;
  int mnX = W_, mxX = -1, mnY = H_, mxY = -1;
  for (int j = tid; j < F4PB; j += 256) {
    int i = slot*F4PB + j;
    float4 a = w0[i], b = w1[i], c = w2[i];
    int m0 = (a.x != 0.f && b.x != 0.f && c.x != 0.f);
    int m1 = (a.y != 0.f && b.y != 0.f && c.y != 0.f);
    int m2 = (a.z != 0.f && b.z != 0.f && c.z != 0.f);
    int m3 = (a.w != 0.f && b.w != 0.f && c.w != 0.f);
    if (useMask) {
      int nib = m0 | (m1<<1) | (m2<<2) | (m3<<3);
      int nxt = __shfl(nib, lane + 1, 64);
      if ((lane & 1) == 0)
        mbs[i >> 1] = (unsigned char)(nib | (nxt << 4));
    }
    if (m0 | m1 | m2 | m3) {
      int y  = i / 112;
      int x0 = (i - y*112) * 4;
      mnY = min(mnY, y); mxY = max(mxY, y);
      int first = m0 ? 0 : (m1 ? 1 : (m2 ? 2 : 3));
      int last  = m3 ? 3 : (m2 ? 2 : (m1 ? 1 : 0));
      mnX = min(mnX, x0 + first);
      mxX = max(mxX, x0 + last);
    }
  }
  __shared__ int sr[4][256];
  sr[0][tid]=mnX; sr[1][tid]=mxX; sr[2][tid]=mnY; sr[3][tid]=mxY;
  __syncthreads();
  for (int off = 128; off > 0; off >>= 1) {
    if (tid < off) {
      sr[0][tid] = min(sr[0][tid], sr[0][tid+off]);
      sr[1][tid] = max(sr[1][tid], sr[1][tid+off]);
      sr[2][tid] = min(sr[2][tid], sr[2][tid+off]);
      sr[3][tid] = max(sr[3][tid], sr[3][tid+off]);
    }
    __syncthreads();
  }
  if (tid == 0) {
    pb[blk*4+0] = sr[0][0]; pb[blk*4+1] = sr[1][0];
    pb[blk*4+2] = sr[2][0]; pb[blk*4+3] = sr[3][0];
  }
}

// ---------------- K2: compose + ballot-gated gathers + nontemporal bm stream ----------------
__global__ void k2_compose(const float* __restrict__ img, const float* __restrict__ bg,
                           const float* __restrict__ wc, const unsigned char* __restrict__ maskbits,
                           const float* __restrict__ col, const float* __restrict__ bri,
                           const int* __restrict__ pb, const int* __restrict__ cbuf,
                           const float* __restrict__ bm, float* __restrict__ bmout,
                           __half* __restrict__ xh, float* __restrict__ xout,
                           float* __restrict__ gpart, int useMask, int useHalf) {
  int tid = threadIdx.x, blk = blockIdx.x;
  int s = blk >> 8;                 // 256 blocks per sample (one output row each)
  int slot = blk & 255;
  int p = (slot << 8) | tid;        // pixel in plane
  int py = slot, px = tid;

  // ---- bm stream: ISSUE NONTEMPORAL LOADS FIRST (consumed at the very end) ----
  const fx4* bm4 = (const fx4*)(bm + (size_t)s*2*HW_);
  int j0 = slot*BM4PB + tid;
  int j1 = j0 + 256;
  bool h1 = (tid + 256) < BM4PB;    // tid < 136
  fx4 bv0 = __builtin_nontemporal_load(bm4 + j0);
  fx4 bv1 = h1 ? __builtin_nontemporal_load(bm4 + j1) : (fx4){0.f,0.f,0.f,0.f};

  Params P = make_params(pb, cbuf, s);
  float colr = col[s*3+0], colg = col[s*3+1], colb = col[s*3+2];
  float brf = bri[s];

  float sy = fmaxf((py + 0.5f) * P.scY - 0.5f, 0.f);
  int   y0 = (int)sy;
  float wy = sy - (float)y0;
  y0 = min(y0, P.Hp - 1);
  int y1 = min(y0 + 1, P.Hp - 1);

  float sx = fmaxf((px + 0.5f) * P.scX - 0.5f, 0.f);
  int   x0 = (int)sx;
  float wx = sx - (float)x0;
  x0 = min(x0, P.Wp - 1);
  int x1 = min(x0 + 1, P.Wp - 1);

  const float* imgb = img + (size_t)s*3*HW_;
  const float* bgb  = bg  + (size_t)s*3*HB_*WB_;
  const float* w0p  = wc  + (size_t)s*3*HW_;
  const unsigned char* mbs = maskbits + (size_t)s*MBPS;

  int oy0 = y0 - P.c2 + P.miny, oy1 = y1 - P.c2 + P.miny;
  int ox0 = x0 - P.c0 + P.minx, ox1 = x1 - P.c0 + P.minx;
  bool vy0 = (oy0 >= P.miny) && (oy0 <= P.maxy);
  bool vy1 = (oy1 >= P.miny) && (oy1 <= P.maxy);
  bool vx0 = (ox0 >= P.minx) && (ox0 <= P.maxx);
  bool vx1 = (ox1 >= P.minx) && (ox1 <= P.maxx);
  int oy0c = min(max(oy0, 0), H_-1), oy1c = min(max(oy1, 0), H_-1);
  int ox0c = min(max(ox0, 0), W_-1), ox1c = min(max(ox1, 0), W_-1);
  int by0 = min(y0, HB_-1), by1 = min(y1, HB_-1);
  int bx0 = min(x0, WB_-1), bx1 = min(x1, WB_-1);

  int mi00 = oy0c*W_ + ox0c, mi01 = oy0c*W_ + ox1c;
  int mi10 = oy1c*W_ + ox0c, mi11 = oy1c*W_ + ox1c;

  // ---- mask first (L2-hot, cheap); gates the heavy gathers ----
  float m00, m01, m10, m11;
  if (useMask) {
    m00 = (float)((mbs[mi00 >> 3] >> (mi00 & 7)) & 1);
    m01 = (float)((mbs[mi01 >> 3] >> (mi01 & 7)) & 1);
    m10 = (float)((mbs[mi10 >> 3] >> (mi10 & 7)) & 1);
    m11 = (float)((mbs[mi11 >> 3] >> (mi11 & 7)) & 1);
  } else {
    m00 = (w0p[mi00] != 0.f && w0p[mi00+HW_] != 0.f && w0p[mi00+2*HW_] != 0.f) ? 1.f : 0.f;
    m01 = (w0p[mi01] != 0.f && w0p[mi01+HW_] != 0.f && w0p[mi01+2*HW_] != 0.f) ? 1.f : 0.f;
    m10 = (w0p[mi10] != 0.f && w0p[mi10+HW_] != 0.f && w0p[mi10+2*HW_] != 0.f) ? 1.f : 0.f;
    m11 = (w0p[mi11] != 0.f && w0p[mi11+HW_] != 0.f && w0p[mi11+2*HW_] != 0.f) ? 1.f : 0.f;
  }
  if (!(vy0 && vx0)) m00 = 0.f;
  if (!(vy0 && vx1)) m01 = 0.f;
  if (!(vy1 && vx0)) m10 = 0.f;
  if (!(vy1 && vx1)) m11 = 0.f;

  // wave-uniform ballots: skip dead gather blocks (no divergence)
  bool needImg = __any(m00 + m01 + m10 + m11 > 0.f);
  bool needBg  = __any(m00 * m01 * m10 * m11 < 1.f);

  float i00[3] = {0.f,0.f,0.f}, i01[3] = {0.f,0.f,0.f};
  float i10[3] = {0.f,0.f,0.f}, i11[3] = {0.f,0.f,0.f};
  if (needImg) {
    #pragma unroll
    for (int ch = 0; ch < 3; ++ch) {
      size_t o = (size_t)ch*HW_;
      i00[ch] = imgb[o + mi00]; i01[ch] = imgb[o + mi01];
      i10[ch] = imgb[o + mi10]; i11[ch] = imgb[o + mi11];
    }
  }

  float g00[3], g01[3], g10[3], g11[3];
  if (P.usebg) {
    if (needBg) {
      size_t b00 = (size_t)by0*WB_ + bx0, b01 = (size_t)by0*WB_ + bx1;
      size_t b10 = (size_t)by1*WB_ + bx0, b11 = (size_t)by1*WB_ + bx1;
      const size_t PL = (size_t)HB_*WB_;
      #pragma unroll
      for (int ch = 0; ch < 3; ++ch) {
        g00[ch] = bgb[b00 + ch*PL];
        g01[ch] = bgb[b01 + ch*PL];
        g10[ch] = bgb[b10 + ch*PL];
        g11[ch] = bgb[b11 + ch*PL];
      }
    } else {
      #pragma unroll
      for (int ch = 0; ch < 3; ++ch) { g00[ch]=g01[ch]=g10[ch]=g11[ch]=0.f; }
    }
  } else {
    g00[0]=g01[0]=g10[0]=g11[0]=colr;
    g00[1]=g01[1]=g10[1]=g11[1]=colg;
    g00[2]=g01[2]=g10[2]=g11[2]=colb;
  }

  float xr[3];
  float gsum;
  {
    #pragma unroll
    for (int ch = 0; ch < 3; ++ch) {
      float a00 = i00[ch]*m00 + g00[ch]*(1.f-m00);
      float a01 = i01[ch]*m01 + g01[ch]*(1.f-m01);
      float a10 = i10[ch]*m10 + g10[ch]*(1.f-m10);
      float a11 = i11[ch]*m11 + g11[ch]*(1.f-m11);
      float top = a00*(1.f-wx) + a01*wx;
      float bot = a10*(1.f-wx) + a11*wx;
      float o = top*(1.f-wy) + bot*wy;
      xr[ch] = clip01(o * brf);
      size_t oi = (size_t)(s*3 + ch)*OO_ + p;
      if (useHalf) xh[oi] = __float2half(xr[ch]);
      else         xout[oi] = xr[ch];
    }
    gsum = 0.299f*xr[0] + 0.587f*xr[1] + 0.114f*xr[2];
  }

  // ---- reduction: wave shuffle + single cross-wave step ----
  #pragma unroll
  for (int off = 32; off > 0; off >>= 1)
    gsum += __shfl_xor(gsum, off, 64);
  __shared__ float swv[4];
  int wv = tid >> 6, lane = tid & 63;
  if (lane == 0) swv[wv] = gsum;
  __syncthreads();
  if (tid == 0) gpart[blk] = swv[0] + swv[1] + swv[2] + swv[3];

  // ---- bm stream: transform + nontemporal store ----
  {
    fx4* out4 = (fx4*)(bmout + (size_t)s*2*HW_);
    float invx = 2.f / P.szx, invy = 2.f / P.szy;
    {
      float off_ = (j0 < F4PP) ? P.offx : P.offy;
      float inv  = (j0 < F4PP) ? invx  : invy;
      fx4 o;
      o.x = (bv0.x - off_) * inv - 1.f;
      o.y = (bv0.y - off_) * inv - 1.f;
      o.z = (bv0.z - off_) * inv - 1.f;
      o.w = (bv0.w - off_) * inv - 1.f;
      __builtin_nontemporal_store(o, out4 + j0);
    }
    if (h1) {
      float off_ = (j1 < F4PP) ? P.offx : P.offy;
      float inv  = (j1 < F4PP) ? invx  : invy;
      fx4 o;
      o.x = (bv1.x - off_) * inv - 1.f;
      o.y = (bv1.y - off_) * inv - 1.f;
      o.z = (bv1.z - off_) * inv - 1.f;
      o.w = (bv1.w - off_) * inv - 1.f;
      __builtin_nontemporal_store(o, out4 + j1);
    }
  }
}

// ---------------- KB: mean + contrast/saturation/hue, 4 px/thread ----------------
__global__ void kb_color(const __half* __restrict__ xh, const float* __restrict__ gpart,
                         const float* __restrict__ con, const float* __restrict__ sat,
                         const float* __restrict__ hue, float* __restrict__ xout,
                         int useHalf) {
  int tid = threadIdx.x, blk = blockIdx.x;
  int s = blk >> 6, slot = blk & 63;
  int u = slot*256 + tid;           // 4-px unit within plane [0, 16384)

  float sum = 0.f;
  for (int t = 0; t < 256; ++t) sum += gpart[s*256 + t];
  float mean = sum * (1.f / (float)OO_);
  float cf = con[s], sfc = sat[s], hu = hue[s];

  float in[3][4];
  #pragma unroll
  for (int ch = 0; ch < 3; ++ch) {
    size_t base = (size_t)(s*3 + ch)*OO_ + (size_t)u*4;
    if (useHalf) {
      uint2 q = ((const uint2*)xh)[base >> 2];
      __half2 h01 = *(__half2*)&q.x;
      __half2 h23 = *(__half2*)&q.y;
      float2 f01 = __half22float2(h01);
      float2 f23 = __half22float2(h23);
      in[ch][0]=f01.x; in[ch][1]=f01.y; in[ch][2]=f23.x; in[ch][3]=f23.y;
    } else {
      float4 f = ((const float4*)xout)[base >> 2];
      in[ch][0]=f.x; in[ch][1]=f.y; in[ch][2]=f.z; in[ch][3]=f.w;
    }
  }

  float ro[4], go[4], bo[4];
  #pragma unroll
  for (int l = 0; l < 4; ++l) {
    float r = in[0][l], g = in[1][l], bl = in[2][l];
    r  = clip01(cf*r  + (1.f-cf)*mean);
    g  = clip01(cf*g  + (1.f-cf)*mean);
    bl = clip01(cf*bl + (1.f-cf)*mean);

    float gr = 0.299f*r + 0.587f*g + 0.114f*bl;
    r  = clip01(sfc*r  + (1.f-sfc)*gr);
    g  = clip01(sfc*g  + (1.f-sfc)*gr);
    bl = clip01(sfc*bl + (1.f-sfc)*gr);

    const float eps = 1e-8f;
    float mx = fmaxf(r, fmaxf(g, bl));
    float mn = fminf(r, fminf(g, bl));
    float d  = mx - mn;
    float inv = 1.f / (d + eps);
    float h;
    if (mx == r)      h = pmodf_((g - bl) * inv, 6.f);
    else if (mx == g) h = (bl - r) * inv + 2.f;
    else              h = (r - g) * inv + 4.f;
    h *= (1.f/6.f);
    if (d <= eps) h = 0.f;
    float sv = d / (mx + eps);
    float v  = mx;

    h = pmodf_(h + hu, 1.f);

    float h6 = pmodf_(h, 1.f) * 6.f;
    float fi = floorf(h6);
    float f  = h6 - fi;
    int   i6 = ((int)fi) % 6;
    float pp = v * (1.f - sv);
    float q  = v * (1.f - f*sv);
    float t  = v * (1.f - (1.f - f)*sv);
    float rr, gg, bb;
    switch (i6) {
      case 0:  rr=v;  gg=t;  bb=pp; break;
      case 1:  rr=q;  gg=v;  bb=pp; break;
      case 2:  rr=pp; gg=v;  bb=t;  break;
      case 3:  rr=pp; gg=q;  bb=v;  break;
      case 4:  rr=t;  gg=pp; bb=v;  break;
      default: rr=v;  gg=pp; bb=q;  break;
    }
    ro[l] = clip01(rr); go[l] = clip01(gg); bo[l] = clip01(bb);
  }
  size_t ub = (size_t)(s*3)*OO_ + (size_t)u*4;
  ((float4*)xout)[(ub)                 >> 2] = make_float4(ro[0],ro[1],ro[2],ro[3]);
  ((float4*)xout)[(ub +   (size_t)OO_) >> 2] = make_float4(go[0],go[1],go[2],go[3]);
  ((float4*)xout)[(ub + 2*(size_t)OO_) >> 2] = make_float4(bo[0],bo[1],bo[2],bo[3]);
}

extern "C" void kernel_launch(void* const* d_in, const int* in_sizes, int n_in,
                              void* d_out, int out_size, void* d_ws, size_t ws_size,
                              hipStream_t stream) {
  const float* img = (const float*)d_in[0];
  const float* wc  = (const float*)d_in[1];
  const float* bm  = (const float*)d_in[2];
  const float* bg  = (const float*)d_in[3];
  const float* col = (const float*)d_in[4];
  const float* bri = (const float*)d_in[5];
  const float* con = (const float*)d_in[6];
  const float* sat = (const float*)d_in[7];
  const float* hue = (const float*)d_in[8];
  const int*   cb  = (const int*)d_in[9];

  float* outx  = (float*)d_out;
  float* outbm = outx + (size_t)B_*3*OO_;

  char* ws = (char*)d_ws;
  int*   pb    = (int*)ws;                                  // [0, 16384)
  float* gpart = (float*)(ws + 16384);                      // 16384 * 4B = 65536
  unsigned char* maskbits = (unsigned char*)(ws + 81920);   // 1,605,632 B
  __half* xh = (__half*)(ws + 1687552);                     // 25,165,824 B

  size_t needMask = 81920 + (size_t)B_*MBPS;                // ~1.69 MB
  size_t needHalf = 1687552 + (size_t)B_*3*OO_*2;           // ~26.9 MB
  int useMask = (ws_size >= needMask) ? 1 : 0;
  int useHalf = (ws_size >= needHalf) ? 1 : 0;

  k1_bboxmask<<<1024,  256, 0, stream>>>(wc, maskbits, pb, useMask);
  k2_compose <<<16384, 256, 0, stream>>>(img, bg, wc, maskbits, col, bri, pb, cb,
                                         bm, outbm, xh, outx, gpart,
                                         useMask, useHalf);
  kb_color   <<<4096,  256, 0, stream>>>(xh, gpart, con, sat, hue, outx, useHalf);
}

// Round 12
// 125.394 us; speedup vs baseline: 1.2244x; 1.1558x over previous
//
#include <hip/hip_runtime.h>
#include <hip/hip_fp16.h>

#define B_    64
#define H_    448
#define W_    448
#define OUT_  256
#define HB_   486
#define WB_   486
#define HW_   (H_*W_)        // 200704
#define OO_   (OUT_*OUT_)    // 65536
#define F4PP  (HW_/4)        // 50176 float4 per channel plane
#define F4PB  (F4PP/16)      // 3136 float4 per K1 block per plane
#define MBPS  (HW_/8)        // 25088 mask bytes per sample (bit-packed)
#define BMF4S (2*HW_/4)      // 100352 float4 per sample (bm)
#define BM4PB (BMF4S/256)    // 392 float4 per k2 block

typedef float fx4 __attribute__((ext_vector_type(4)));
typedef unsigned long long u64;

__device__ __forceinline__ float clip01(float v) { return fminf(fmaxf(v, 0.f), 1.f); }
__device__ __forceinline__ float pmodf_(float a, float m) {
  float r = fmodf(a, m);
  return (r < 0.f) ? r + m : r;
}

struct Params {
  int minx, miny, maxx, maxy, c0, c2, usebg, Hp, Wp;
  float scX, scY, offx, szx, offy, szy;
};

// uniform per-block param recompute (all addresses uniform -> scalar loads)
__device__ __forceinline__ Params make_params(const int* __restrict__ pb,
                                              const int* __restrict__ cbuf, int s) {
  int mnX = W_, mxX = -1, mnY = H_, mxY = -1;
  #pragma unroll
  for (int t = 0; t < 16; ++t) {
    int base = (s*16 + t) * 4;
    mnX = min(mnX, pb[base+0]); mxX = max(mxX, pb[base+1]);
    mnY = min(mnY, pb[base+2]); mxY = max(mxY, pb[base+3]);
  }
  if (mxY < 0) { mnY = 0; mxY = H_-1; }
  if (mxX < 0) { mnX = 0; mxX = W_-1; }
  int c0 = cbuf[s*5+0], c1 = cbuf[s*5+1], c2 = cbuf[s*5+2],
      c3 = cbuf[s*5+3], c4 = cbuf[s*5+4];
  Params P;
  P.minx = mnX; P.miny = mnY; P.maxx = mxX; P.maxy = mxY;
  P.c0 = c0; P.c2 = c2; P.usebg = (c4 > 2);
  P.Hp = mxY - mnY + 1 + c2 + c3;
  P.Wp = mxX - mnX + 1 + c0 + c1;
  P.scX = (float)P.Wp / (float)OUT_;
  P.scY = (float)P.Hp / (float)OUT_;
  P.offx = (float)(mnX - c0); P.szx = (float)P.Wp;
  P.offy = (float)(mnY - c2); P.szy = (float)P.Hp;
  return P;
}

// ---------------- K1: bit-packed mask + bbox block partials (NT wc reads) ----------------
__global__ void k1_bboxmask(const float* __restrict__ wc, unsigned char* __restrict__ maskbits,
                            int* __restrict__ pb, int useMask) {
  int blk = blockIdx.x, tid = threadIdx.x;
  int s = blk >> 4, slot = blk & 15;
  const fx4* w0 = (const fx4*)(wc + (size_t)s*3*HW_);
  const fx4* w1 = w0 + F4PP;
  const fx4* w2 = w1 + F4PP;
  unsigned char* mbs = maskbits + (size_t)s*MBPS;
  int lane = tid & 63;
  int mnX = W_, mxX = -1, mnY = H_, mxY = -1;
  for (int j = tid; j < F4PB; j += 256) {
    int i = slot*F4PB + j;
    fx4 a = __builtin_nontemporal_load(w0 + i);
    fx4 b = __builtin_nontemporal_load(w1 + i);
    fx4 c = __builtin_nontemporal_load(w2 + i);
    int m0 = (a.x != 0.f && b.x != 0.f && c.x != 0.f);
    int m1 = (a.y != 0.f && b.y != 0.f && c.y != 0.f);
    int m2 = (a.z != 0.f && b.z != 0.f && c.z != 0.f);
    int m3 = (a.w != 0.f && b.w != 0.f && c.w != 0.f);
    if (useMask) {
      int nib = m0 | (m1<<1) | (m2<<2) | (m3<<3);
      int nxt = __shfl(nib, lane + 1, 64);
      if ((lane & 1) == 0)
        mbs[i >> 1] = (unsigned char)(nib | (nxt << 4));
    }
    if (m0 | m1 | m2 | m3) {
      int y  = i / 112;
      int x0 = (i - y*112) * 4;
      mnY = min(mnY, y); mxY = max(mxY, y);
      int first = m0 ? 0 : (m1 ? 1 : (m2 ? 2 : 3));
      int last  = m3 ? 3 : (m2 ? 2 : (m1 ? 1 : 0));
      mnX = min(mnX, x0 + first);
      mxX = max(mxX, x0 + last);
    }
  }
  __shared__ int sr[4][256];
  sr[0][tid]=mnX; sr[1][tid]=mxX; sr[2][tid]=mnY; sr[3][tid]=mxY;
  __syncthreads();
  for (int off = 128; off > 0; off >>= 1) {
    if (tid < off) {
      sr[0][tid] = min(sr[0][tid], sr[0][tid+off]);
      sr[1][tid] = max(sr[1][tid], sr[1][tid+off]);
      sr[2][tid] = min(sr[2][tid], sr[2][tid+off]);
      sr[3][tid] = max(sr[3][tid], sr[3][tid+off]);
    }
    __syncthreads();
  }
  if (tid == 0) {
    pb[blk*4+0] = sr[0][0]; pb[blk*4+1] = sr[1][0];
    pb[blk*4+2] = sr[2][0]; pb[blk*4+3] = sr[3][0];
  }
}

// ---------------- K2: compose + gated gathers + NT bm/xh + XCD-chunked swizzle ----------------
__global__ void k2_compose(const float* __restrict__ img, const float* __restrict__ bg,
                           const float* __restrict__ wc, const unsigned char* __restrict__ maskbits,
                           const float* __restrict__ col, const float* __restrict__ bri,
                           const int* __restrict__ pb, const int* __restrict__ cbuf,
                           const float* __restrict__ bm, float* __restrict__ bmout,
                           __half* __restrict__ xh, float* __restrict__ xout,
                           float* __restrict__ gpart, int useMask, int useHalf) {
  int tid = threadIdx.x;
  // XCD-chunked swizzle: physical p -> logical bid so each XCD owns a
  // contiguous run of rows (8 samples), capturing row-overlap reuse in its L2.
  // 16384 % 8 == 0 -> bijective.
  int pphys = blockIdx.x;
  int blk = (pphys & 7) * 2048 + (pphys >> 3);
  int s = blk >> 8;                 // 256 blocks per sample (one output row each)
  int slot = blk & 255;
  int p = (slot << 8) | tid;        // pixel in plane
  int py = slot, px = tid;

  // ---- bm stream: ISSUE NONTEMPORAL LOADS FIRST (consumed at the very end) ----
  const fx4* bm4 = (const fx4*)(bm + (size_t)s*2*HW_);
  int j0 = slot*BM4PB + tid;
  int j1 = j0 + 256;
  bool h1 = (tid + 256) < BM4PB;    // tid < 136
  fx4 bv0 = __builtin_nontemporal_load(bm4 + j0);
  fx4 bv1 = h1 ? __builtin_nontemporal_load(bm4 + j1) : (fx4){0.f,0.f,0.f,0.f};

  Params P = make_params(pb, cbuf, s);
  float colr = col[s*3+0], colg = col[s*3+1], colb = col[s*3+2];
  float brf = bri[s];

  float sy = fmaxf((py + 0.5f) * P.scY - 0.5f, 0.f);
  int   y0 = (int)sy;
  float wy = sy - (float)y0;
  y0 = min(y0, P.Hp - 1);
  int y1 = min(y0 + 1, P.Hp - 1);

  float sx = fmaxf((px + 0.5f) * P.scX - 0.5f, 0.f);
  int   x0 = (int)sx;
  float wx = sx - (float)x0;
  x0 = min(x0, P.Wp - 1);
  int x1 = min(x0 + 1, P.Wp - 1);

  const float* imgb = img + (size_t)s*3*HW_;
  const float* bgb  = bg  + (size_t)s*3*HB_*WB_;
  const float* w0p  = wc  + (size_t)s*3*HW_;
  const unsigned char* mbs = maskbits + (size_t)s*MBPS;

  int oy0 = y0 - P.c2 + P.miny, oy1 = y1 - P.c2 + P.miny;
  int ox0 = x0 - P.c0 + P.minx, ox1 = x1 - P.c0 + P.minx;
  bool vy0 = (oy0 >= P.miny) && (oy0 <= P.maxy);
  bool vy1 = (oy1 >= P.miny) && (oy1 <= P.maxy);
  bool vx0 = (ox0 >= P.minx) && (ox0 <= P.maxx);
  bool vx1 = (ox1 >= P.minx) && (ox1 <= P.maxx);
  int oy0c = min(max(oy0, 0), H_-1), oy1c = min(max(oy1, 0), H_-1);
  int ox0c = min(max(ox0, 0), W_-1), ox1c = min(max(ox1, 0), W_-1);
  int by0 = min(y0, HB_-1), by1 = min(y1, HB_-1);
  int bx0 = min(x0, WB_-1), bx1 = min(x1, WB_-1);

  int mi00 = oy0c*W_ + ox0c, mi01 = oy0c*W_ + ox1c;
  int mi10 = oy1c*W_ + ox0c, mi11 = oy1c*W_ + ox1c;

  // ---- mask first (L2-hot, cheap); gates the heavy gathers ----
  float m00, m01, m10, m11;
  if (useMask) {
    m00 = (float)((mbs[mi00 >> 3] >> (mi00 & 7)) & 1);
    m01 = (float)((mbs[mi01 >> 3] >> (mi01 & 7)) & 1);
    m10 = (float)((mbs[mi10 >> 3] >> (mi10 & 7)) & 1);
    m11 = (float)((mbs[mi11 >> 3] >> (mi11 & 7)) & 1);
  } else {
    m00 = (w0p[mi00] != 0.f && w0p[mi00+HW_] != 0.f && w0p[mi00+2*HW_] != 0.f) ? 1.f : 0.f;
    m01 = (w0p[mi01] != 0.f && w0p[mi01+HW_] != 0.f && w0p[mi01+2*HW_] != 0.f) ? 1.f : 0.f;
    m10 = (w0p[mi10] != 0.f && w0p[mi10+HW_] != 0.f && w0p[mi10+2*HW_] != 0.f) ? 1.f : 0.f;
    m11 = (w0p[mi11] != 0.f && w0p[mi11+HW_] != 0.f && w0p[mi11+2*HW_] != 0.f) ? 1.f : 0.f;
  }
  if (!(vy0 && vx0)) m00 = 0.f;
  if (!(vy0 && vx1)) m01 = 0.f;
  if (!(vy1 && vx0)) m10 = 0.f;
  if (!(vy1 && vx1)) m11 = 0.f;

  // wave-uniform ballots: skip dead gather blocks (no divergence)
  bool needImg = __any(m00 + m01 + m10 + m11 > 0.f);
  bool needBg  = __any(m00 * m01 * m10 * m11 < 1.f);

  float i00[3] = {0.f,0.f,0.f}, i01[3] = {0.f,0.f,0.f};
  float i10[3] = {0.f,0.f,0.f}, i11[3] = {0.f,0.f,0.f};
  if (needImg) {
    #pragma unroll
    for (int ch = 0; ch < 3; ++ch) {
      size_t o = (size_t)ch*HW_;
      i00[ch] = imgb[o + mi00]; i01[ch] = imgb[o + mi01];
      i10[ch] = imgb[o + mi10]; i11[ch] = imgb[o + mi11];
    }
  }

  float g00[3], g01[3], g10[3], g11[3];
  if (P.usebg) {
    if (needBg) {
      size_t b00 = (size_t)by0*WB_ + bx0, b01 = (size_t)by0*WB_ + bx1;
      size_t b10 = (size_t)by1*WB_ + bx0, b11 = (size_t)by1*WB_ + bx1;
      const size_t PL = (size_t)HB_*WB_;
      #pragma unroll
      for (int ch = 0; ch < 3; ++ch) {
        g00[ch] = bgb[b00 + ch*PL];
        g01[ch] = bgb[b01 + ch*PL];
        g10[ch] = bgb[b10 + ch*PL];
        g11[ch] = bgb[b11 + ch*PL];
      }
    } else {
      #pragma unroll
      for (int ch = 0; ch < 3; ++ch) { g00[ch]=g01[ch]=g10[ch]=g11[ch]=0.f; }
    }
  } else {
    g00[0]=g01[0]=g10[0]=g11[0]=colr;
    g00[1]=g01[1]=g10[1]=g11[1]=colg;
    g00[2]=g01[2]=g10[2]=g11[2]=colb;
  }

  float xr[3];
  float gsum;
  {
    #pragma unroll
    for (int ch = 0; ch < 3; ++ch) {
      float a00 = i00[ch]*m00 + g00[ch]*(1.f-m00);
      float a01 = i01[ch]*m01 + g01[ch]*(1.f-m01);
      float a10 = i10[ch]*m10 + g10[ch]*(1.f-m10);
      float a11 = i11[ch]*m11 + g11[ch]*(1.f-m11);
      float top = a00*(1.f-wx) + a01*wx;
      float bot = a10*(1.f-wx) + a11*wx;
      float o = top*(1.f-wy) + bot*wy;
      xr[ch] = clip01(o * brf);
      size_t oi = (size_t)(s*3 + ch)*OO_ + p;
      if (useHalf) {
        __half hv = __float2half(xr[ch]);
        __builtin_nontemporal_store(*(const unsigned short*)&hv,
                                    (unsigned short*)(xh + oi));
      } else {
        xout[oi] = xr[ch];
      }
    }
    gsum = 0.299f*xr[0] + 0.587f*xr[1] + 0.114f*xr[2];
  }

  // ---- reduction: wave shuffle + single cross-wave step ----
  #pragma unroll
  for (int off = 32; off > 0; off >>= 1)
    gsum += __shfl_xor(gsum, off, 64);
  __shared__ float swv[4];
  int wv = tid >> 6, lane = tid & 63;
  if (lane == 0) swv[wv] = gsum;
  __syncthreads();
  if (tid == 0) gpart[blk] = swv[0] + swv[1] + swv[2] + swv[3];

  // ---- bm stream: transform + nontemporal store ----
  {
    fx4* out4 = (fx4*)(bmout + (size_t)s*2*HW_);
    float invx = 2.f / P.szx, invy = 2.f / P.szy;
    {
      float off_ = (j0 < F4PP) ? P.offx : P.offy;
      float inv  = (j0 < F4PP) ? invx  : invy;
      fx4 o;
      o.x = (bv0.x - off_) * inv - 1.f;
      o.y = (bv0.y - off_) * inv - 1.f;
      o.z = (bv0.z - off_) * inv - 1.f;
      o.w = (bv0.w - off_) * inv - 1.f;
      __builtin_nontemporal_store(o, out4 + j0);
    }
    if (h1) {
      float off_ = (j1 < F4PP) ? P.offx : P.offy;
      float inv  = (j1 < F4PP) ? invx  : invy;
      fx4 o;
      o.x = (bv1.x - off_) * inv - 1.f;
      o.y = (bv1.y - off_) * inv - 1.f;
      o.z = (bv1.z - off_) * inv - 1.f;
      o.w = (bv1.w - off_) * inv - 1.f;
      __builtin_nontemporal_store(o, out4 + j1);
    }
  }
}

// ---------------- KB: mean + contrast/saturation/hue, 4 px/thread (NT IO) ----------------
__global__ void kb_color(const __half* __restrict__ xh, const float* __restrict__ gpart,
                         const float* __restrict__ con, const float* __restrict__ sat,
                         const float* __restrict__ hue, float* __restrict__ xout,
                         int useHalf) {
  int tid = threadIdx.x, blk = blockIdx.x;
  int s = blk >> 6, slot = blk & 63;
  int u = slot*256 + tid;           // 4-px unit within plane [0, 16384)

  float sum = 0.f;
  for (int t = 0; t < 256; ++t) sum += gpart[s*256 + t];
  float mean = sum * (1.f / (float)OO_);
  float cf = con[s], sfc = sat[s], hu = hue[s];

  float in[3][4];
  #pragma unroll
  for (int ch = 0; ch < 3; ++ch) {
    size_t base = (size_t)(s*3 + ch)*OO_ + (size_t)u*4;
    if (useHalf) {
      u64 q = __builtin_nontemporal_load((const u64*)(xh + base));
      unsigned q0 = (unsigned)q, q1 = (unsigned)(q >> 32);
      __half2 h01 = *(__half2*)&q0;
      __half2 h23 = *(__half2*)&q1;
      float2 f01 = __half22float2(h01);
      float2 f23 = __half22float2(h23);
      in[ch][0]=f01.x; in[ch][1]=f01.y; in[ch][2]=f23.x; in[ch][3]=f23.y;
    } else {
      float4 f = ((const float4*)xout)[base >> 2];
      in[ch][0]=f.x; in[ch][1]=f.y; in[ch][2]=f.z; in[ch][3]=f.w;
    }
  }

  float ro[4], go[4], bo[4];
  #pragma unroll
  for (int l = 0; l < 4; ++l) {
    float r = in[0][l], g = in[1][l], bl = in[2][l];
    r  = clip01(cf*r  + (1.f-cf)*mean);
    g  = clip01(cf*g  + (1.f-cf)*mean);
    bl = clip01(cf*bl + (1.f-cf)*mean);

    float gr = 0.299f*r + 0.587f*g + 0.114f*bl;
    r  = clip01(sfc*r  + (1.f-sfc)*gr);
    g  = clip01(sfc*g  + (1.f-sfc)*gr);
    bl = clip01(sfc*bl + (1.f-sfc)*gr);

    const float eps = 1e-8f;
    float mx = fmaxf(r, fmaxf(g, bl));
    float mn = fminf(r, fminf(g, bl));
    float d  = mx - mn;
    float inv = 1.f / (d + eps);
    float h;
    if (mx == r)      h = pmodf_((g - bl) * inv, 6.f);
    else if (mx == g) h = (bl - r) * inv + 2.f;
    else              h = (r - g) * inv + 4.f;
    h *= (1.f/6.f);
    if (d <= eps) h = 0.f;
    float sv = d / (mx + eps);
    float v  = mx;

    h = pmodf_(h + hu, 1.f);

    float h6 = pmodf_(h, 1.f) * 6.f;
    float fi = floorf(h6);
    float f  = h6 - fi;
    int   i6 = ((int)fi) % 6;
    float pp = v * (1.f - sv);
    float q  = v * (1.f - f*sv);
    float t  = v * (1.f - (1.f - f)*sv);
    float rr, gg, bb;
    switch (i6) {
      case 0:  rr=v;  gg=t;  bb=pp; break;
      case 1:  rr=q;  gg=v;  bb=pp; break;
      case 2:  rr=pp; gg=v;  bb=t;  break;
      case 3:  rr=pp; gg=q;  bb=v;  break;
      case 4:  rr=t;  gg=pp; bb=v;  break;
      default: rr=v;  gg=pp; bb=q;  break;
    }
    ro[l] = clip01(rr); go[l] = clip01(gg); bo[l] = clip01(bb);
  }
  size_t ub = (size_t)(s*3)*OO_ + (size_t)u*4;
  fx4 vr = {ro[0],ro[1],ro[2],ro[3]};
  fx4 vg = {go[0],go[1],go[2],go[3]};
  fx4 vb = {bo[0],bo[1],bo[2],bo[3]};
  __builtin_nontemporal_store(vr, (fx4*)xout + ((ub)                 >> 2));
  __builtin_nontemporal_store(vg, (fx4*)xout + ((ub +   (size_t)OO_) >> 2));
  __builtin_nontemporal_store(vb, (fx4*)xout + ((ub + 2*(size_t)OO_) >> 2));
}

extern "C" void kernel_launch(void* const* d_in, const int* in_sizes, int n_in,
                              void* d_out, int out_size, void* d_ws, size_t ws_size,
                              hipStream_t stream) {
  const float* img = (const float*)d_in[0];
  const float* wc  = (const float*)d_in[1];
  const float* bm  = (const float*)d_in[2];
  const float* bg  = (const float*)d_in[3];
  const float* col = (const float*)d_in[4];
  const float* bri = (const float*)d_in[5];
  const float* con = (const float*)d_in[6];
  const float* sat = (const float*)d_in[7];
  const float* hue = (const float*)d_in[8];
  const int*   cb  = (const int*)d_in[9];

  float* outx  = (float*)d_out;
  float* outbm = outx + (size_t)B_*3*OO_;

  char* ws = (char*)d_ws;
  int*   pb    = (int*)ws;                                  // [0, 16384)
  float* gpart = (float*)(ws + 16384);                      // 16384 * 4B = 65536
  unsigned char* maskbits = (unsigned char*)(ws + 81920);   // 1,605,632 B
  __half* xh = (__half*)(ws + 1687552);                     // 25,165,824 B

  size_t needMask = 81920 + (size_t)B_*MBPS;                // ~1.69 MB
  size_t needHalf = 1687552 + (size_t)B_*3*OO_*2;           // ~26.9 MB
  int useMask = (ws_size >= needMask) ? 1 : 0;
  int useHalf = (ws_size >= needHalf) ? 1 : 0;

  k1_bboxmask<<<1024,  256, 0, stream>>>(wc, maskbits, pb, useMask);
  k2_compose <<<16384, 256, 0, stream>>>(img, bg, wc, maskbits, col, bri, pb, cb,
                                         bm, outbm, xh, outx, gpart,
                                         useMask, useHalf);
  kb_color   <<<4096,  256, 0, stream>>>(xh, gpart, con, sat, hue, outx, useHalf);
}

// Round 13
// 125.023 us; speedup vs baseline: 1.2280x; 1.0030x over previous
//
#include <hip/hip_runtime.h>
#include <hip/hip_fp16.h>

#define B_    64
#define H_    448
#define W_    448
#define OUT_  256
#define HB_   486
#define WB_   486
#define HW_   (H_*W_)        // 200704
#define OO_   (OUT_*OUT_)    // 65536
#define F4PP  (HW_/4)        // 50176 float4 per channel plane
#define F4PB  (F4PP/16)      // 3136 float4 per K1 block per plane
#define MBPS  (HW_/8)        // 25088 mask bytes per sample (bit-packed)
#define BMF4S (2*HW_/4)      // 100352 float4 per sample (bm)
#define BM4PB (BMF4S/256)    // 392 float4 per k2 block

typedef float fx4 __attribute__((ext_vector_type(4)));
typedef unsigned long long u64;

__device__ __forceinline__ float clip01(float v) { return fminf(fmaxf(v, 0.f), 1.f); }
__device__ __forceinline__ float pmodf_(float a, float m) {
  float r = fmodf(a, m);
  return (r < 0.f) ? r + m : r;
}

struct Params {
  int minx, miny, maxx, maxy, c0, c2, usebg, Hp, Wp;
  float scX, scY, offx, szx, offy, szy;
  int pad;
};

// ---------------- K1: bit-packed mask + bbox partials, gated wc1/wc2 reads ----------------
__global__ void k1_bboxmask(const float* __restrict__ wc, unsigned char* __restrict__ maskbits,
                            int* __restrict__ pb, int useMask) {
  int blk = blockIdx.x, tid = threadIdx.x;
  int s = blk >> 4, slot = blk & 15;
  const fx4* w0 = (const fx4*)(wc + (size_t)s*3*HW_);
  const fx4* w1 = w0 + F4PP;
  const fx4* w2 = w1 + F4PP;
  unsigned char* mbs = maskbits + (size_t)s*MBPS;
  int lane = tid & 63;
  int mnX = W_, mxX = -1, mnY = H_, mxY = -1;
  for (int j = tid; j < F4PB; j += 256) {
    int i = slot*F4PB + j;
    fx4 a = __builtin_nontemporal_load(w0 + i);
    bool nz0 = (a.x != 0.f) || (a.y != 0.f) || (a.z != 0.f) || (a.w != 0.f);
    int m0 = 0, m1 = 0, m2 = 0, m3 = 0;
    // mask = AND of 3 channels; if wave's w0 chunk is all-zero, w1/w2 can't
    // flip any bit -> skip those loads (correct for any input).
    if (__any(nz0)) {
      fx4 b = __builtin_nontemporal_load(w1 + i);
      fx4 c = __builtin_nontemporal_load(w2 + i);
      m0 = (a.x != 0.f && b.x != 0.f && c.x != 0.f);
      m1 = (a.y != 0.f && b.y != 0.f && c.y != 0.f);
      m2 = (a.z != 0.f && b.z != 0.f && c.z != 0.f);
      m3 = (a.w != 0.f && b.w != 0.f && c.w != 0.f);
    }
    if (useMask) {
      int nib = m0 | (m1<<1) | (m2<<2) | (m3<<3);
      int nxt = __shfl(nib, lane + 1, 64);
      if ((lane & 1) == 0)
        mbs[i >> 1] = (unsigned char)(nib | (nxt << 4));
    }
    if (m0 | m1 | m2 | m3) {
      int y  = i / 112;
      int x0 = (i - y*112) * 4;
      mnY = min(mnY, y); mxY = max(mxY, y);
      int first = m0 ? 0 : (m1 ? 1 : (m2 ? 2 : 3));
      int last  = m3 ? 3 : (m2 ? 2 : (m1 ? 1 : 0));
      mnX = min(mnX, x0 + first);
      mxX = max(mxX, x0 + last);
    }
  }
  __shared__ int sr[4][256];
  sr[0][tid]=mnX; sr[1][tid]=mxX; sr[2][tid]=mnY; sr[3][tid]=mxY;
  __syncthreads();
  for (int off = 128; off > 0; off >>= 1) {
    if (tid < off) {
      sr[0][tid] = min(sr[0][tid], sr[0][tid+off]);
      sr[1][tid] = max(sr[1][tid], sr[1][tid+off]);
      sr[2][tid] = min(sr[2][tid], sr[2][tid+off]);
      sr[3][tid] = max(sr[3][tid], sr[3][tid+off]);
    }
    __syncthreads();
  }
  if (tid == 0) {
    pb[blk*4+0] = sr[0][0]; pb[blk*4+1] = sr[1][0];
    pb[blk*4+2] = sr[2][0]; pb[blk*4+3] = sr[3][0];
  }
}

// ---------------- K0: per-sample param table (one tiny block) ----------------
__global__ void k0_params(const int* __restrict__ pb, const int* __restrict__ cbuf,
                          Params* __restrict__ ptab) {
  int b = threadIdx.x;
  if (b >= B_) return;
  int mnX = W_, mxX = -1, mnY = H_, mxY = -1;
  #pragma unroll
  for (int t = 0; t < 16; ++t) {
    int base = (b*16 + t) * 4;
    mnX = min(mnX, pb[base+0]); mxX = max(mxX, pb[base+1]);
    mnY = min(mnY, pb[base+2]); mxY = max(mxY, pb[base+3]);
  }
  if (mxY < 0) { mnY = 0; mxY = H_-1; }
  if (mxX < 0) { mnX = 0; mxX = W_-1; }
  int c0 = cbuf[b*5+0], c1 = cbuf[b*5+1], c2 = cbuf[b*5+2],
      c3 = cbuf[b*5+3], c4 = cbuf[b*5+4];
  Params P;
  P.minx = mnX; P.miny = mnY; P.maxx = mxX; P.maxy = mxY;
  P.c0 = c0; P.c2 = c2; P.usebg = (c4 > 2);
  P.Hp = mxY - mnY + 1 + c2 + c3;
  P.Wp = mxX - mnX + 1 + c0 + c1;
  P.scX = (float)P.Wp / (float)OUT_;
  P.scY = (float)P.Hp / (float)OUT_;
  P.offx = (float)(mnX - c0); P.szx = (float)P.Wp;
  P.offy = (float)(mnY - c2); P.szy = (float)P.Hp;
  P.pad = 0;
  ptab[b] = P;
}

// ---------------- K2: compose + gated gathers + NT bm/xh + XCD-chunked swizzle ----------------
__global__ void k2_compose(const float* __restrict__ img, const float* __restrict__ bg,
                           const float* __restrict__ wc, const unsigned char* __restrict__ maskbits,
                           const float* __restrict__ col, const float* __restrict__ bri,
                           const Params* __restrict__ ptab,
                           const float* __restrict__ bm, float* __restrict__ bmout,
                           __half* __restrict__ xh, float* __restrict__ xout,
                           float* __restrict__ gpart, int useMask, int useHalf) {
  int tid = threadIdx.x;
  // XCD-chunked swizzle (16384 % 8 == 0 -> bijective)
  int pphys = blockIdx.x;
  int blk = (pphys & 7) * 2048 + (pphys >> 3);
  int s = blk >> 8;
  int slot = blk & 255;
  int p = (slot << 8) | tid;
  int py = slot, px = tid;

  // ---- bm stream: issue NT loads first (no dependencies) ----
  const fx4* bm4 = (const fx4*)(bm + (size_t)s*2*HW_);
  int j0 = slot*BM4PB + tid;
  int j1 = j0 + 256;
  bool h1 = (tid + 256) < BM4PB;
  fx4 bv0 = __builtin_nontemporal_load(bm4 + j0);
  fx4 bv1 = h1 ? __builtin_nontemporal_load(bm4 + j1) : (fx4){0.f,0.f,0.f,0.f};

  Params P = ptab[s];
  float colr = col[s*3+0], colg = col[s*3+1], colb = col[s*3+2];
  float brf = bri[s];

  float sy = fmaxf((py + 0.5f) * P.scY - 0.5f, 0.f);
  int   y0 = (int)sy;
  float wy = sy - (float)y0;
  y0 = min(y0, P.Hp - 1);
  int y1 = min(y0 + 1, P.Hp - 1);

  float sx = fmaxf((px + 0.5f) * P.scX - 0.5f, 0.f);
  int   x0 = (int)sx;
  float wx = sx - (float)x0;
  x0 = min(x0, P.Wp - 1);
  int x1 = min(x0 + 1, P.Wp - 1);

  const float* imgb = img + (size_t)s*3*HW_;
  const float* bgb  = bg  + (size_t)s*3*HB_*WB_;
  const float* w0p  = wc  + (size_t)s*3*HW_;
  const unsigned char* mbs = maskbits + (size_t)s*MBPS;

  int oy0 = y0 - P.c2 + P.miny, oy1 = y1 - P.c2 + P.miny;
  int ox0 = x0 - P.c0 + P.minx, ox1 = x1 - P.c0 + P.minx;
  bool vy0 = (oy0 >= P.miny) && (oy0 <= P.maxy);
  bool vy1 = (oy1 >= P.miny) && (oy1 <= P.maxy);
  bool vx0 = (ox0 >= P.minx) && (ox0 <= P.maxx);
  bool vx1 = (ox1 >= P.minx) && (ox1 <= P.maxx);
  int oy0c = min(max(oy0, 0), H_-1), oy1c = min(max(oy1, 0), H_-1);
  int ox0c = min(max(ox0, 0), W_-1), ox1c = min(max(ox1, 0), W_-1);
  int by0 = min(y0, HB_-1), by1 = min(y1, HB_-1);
  int bx0 = min(x0, WB_-1), bx1 = min(x1, WB_-1);

  int mi00 = oy0c*W_ + ox0c, mi01 = oy0c*W_ + ox1c;
  int mi10 = oy1c*W_ + ox0c, mi11 = oy1c*W_ + ox1c;

  // ---- mask first (L2-hot); gates the heavy gathers ----
  float m00, m01, m10, m11;
  if (useMask) {
    m00 = (float)((mbs[mi00 >> 3] >> (mi00 & 7)) & 1);
    m01 = (float)((mbs[mi01 >> 3] >> (mi01 & 7)) & 1);
    m10 = (float)((mbs[mi10 >> 3] >> (mi10 & 7)) & 1);
    m11 = (float)((mbs[mi11 >> 3] >> (mi11 & 7)) & 1);
  } else {
    m00 = (w0p[mi00] != 0.f && w0p[mi00+HW_] != 0.f && w0p[mi00+2*HW_] != 0.f) ? 1.f : 0.f;
    m01 = (w0p[mi01] != 0.f && w0p[mi01+HW_] != 0.f && w0p[mi01+2*HW_] != 0.f) ? 1.f : 0.f;
    m10 = (w0p[mi10] != 0.f && w0p[mi10+HW_] != 0.f && w0p[mi10+2*HW_] != 0.f) ? 1.f : 0.f;
    m11 = (w0p[mi11] != 0.f && w0p[mi11+HW_] != 0.f && w0p[mi11+2*HW_] != 0.f) ? 1.f : 0.f;
  }
  if (!(vy0 && vx0)) m00 = 0.f;
  if (!(vy0 && vx1)) m01 = 0.f;
  if (!(vy1 && vx0)) m10 = 0.f;
  if (!(vy1 && vx1)) m11 = 0.f;

  bool needImg = __any(m00 + m01 + m10 + m11 > 0.f);
  bool needBg  = __any(m00 * m01 * m10 * m11 < 1.f);

  float i00[3] = {0.f,0.f,0.f}, i01[3] = {0.f,0.f,0.f};
  float i10[3] = {0.f,0.f,0.f}, i11[3] = {0.f,0.f,0.f};
  if (needImg) {
    #pragma unroll
    for (int ch = 0; ch < 3; ++ch) {
      size_t o = (size_t)ch*HW_;
      i00[ch] = imgb[o + mi00]; i01[ch] = imgb[o + mi01];
      i10[ch] = imgb[o + mi10]; i11[ch] = imgb[o + mi11];
    }
  }

  float g00[3], g01[3], g10[3], g11[3];
  if (P.usebg) {
    if (needBg) {
      size_t b00 = (size_t)by0*WB_ + bx0, b01 = (size_t)by0*WB_ + bx1;
      size_t b10 = (size_t)by1*WB_ + bx0, b11 = (size_t)by1*WB_ + bx1;
      const size_t PL = (size_t)HB_*WB_;
      #pragma unroll
      for (int ch = 0; ch < 3; ++ch) {
        g00[ch] = bgb[b00 + ch*PL];
        g01[ch] = bgb[b01 + ch*PL];
        g10[ch] = bgb[b10 + ch*PL];
        g11[ch] = bgb[b11 + ch*PL];
      }
    } else {
      #pragma unroll
      for (int ch = 0; ch < 3; ++ch) { g00[ch]=g01[ch]=g10[ch]=g11[ch]=0.f; }
    }
  } else {
    g00[0]=g01[0]=g10[0]=g11[0]=colr;
    g00[1]=g01[1]=g10[1]=g11[1]=colg;
    g00[2]=g01[2]=g10[2]=g11[2]=colb;
  }

  float xr[3];
  float gsum;
  {
    #pragma unroll
    for (int ch = 0; ch < 3; ++ch) {
      float a00 = i00[ch]*m00 + g00[ch]*(1.f-m00);
      float a01 = i01[ch]*m01 + g01[ch]*(1.f-m01);
      float a10 = i10[ch]*m10 + g10[ch]*(1.f-m10);
      float a11 = i11[ch]*m11 + g11[ch]*(1.f-m11);
      float top = a00*(1.f-wx) + a01*wx;
      float bot = a10*(1.f-wx) + a11*wx;
      float o = top*(1.f-wy) + bot*wy;
      xr[ch] = clip01(o * brf);
      size_t oi = (size_t)(s*3 + ch)*OO_ + p;
      if (useHalf) {
        __half hv = __float2half(xr[ch]);
        __builtin_nontemporal_store(*(const unsigned short*)&hv,
                                    (unsigned short*)(xh + oi));
      } else {
        xout[oi] = xr[ch];
      }
    }
    gsum = 0.299f*xr[0] + 0.587f*xr[1] + 0.114f*xr[2];
  }

  // ---- reduction: wave shuffle + single cross-wave step ----
  #pragma unroll
  for (int off = 32; off > 0; off >>= 1)
    gsum += __shfl_xor(gsum, off, 64);
  __shared__ float swv[4];
  int wv = tid >> 6, lane = tid & 63;
  if (lane == 0) swv[wv] = gsum;
  __syncthreads();
  if (tid == 0) gpart[blk] = swv[0] + swv[1] + swv[2] + swv[3];

  // ---- bm stream: transform + NT store ----
  {
    fx4* out4 = (fx4*)(bmout + (size_t)s*2*HW_);
    float invx = 2.f / P.szx, invy = 2.f / P.szy;
    {
      float off_ = (j0 < F4PP) ? P.offx : P.offy;
      float inv  = (j0 < F4PP) ? invx  : invy;
      fx4 o;
      o.x = (bv0.x - off_) * inv - 1.f;
      o.y = (bv0.y - off_) * inv - 1.f;
      o.z = (bv0.z - off_) * inv - 1.f;
      o.w = (bv0.w - off_) * inv - 1.f;
      __builtin_nontemporal_store(o, out4 + j0);
    }
    if (h1) {
      float off_ = (j1 < F4PP) ? P.offx : P.offy;
      float inv  = (j1 < F4PP) ? invx  : invy;
      fx4 o;
      o.x = (bv1.x - off_) * inv - 1.f;
      o.y = (bv1.y - off_) * inv - 1.f;
      o.z = (bv1.z - off_) * inv - 1.f;
      o.w = (bv1.w - off_) * inv - 1.f;
      __builtin_nontemporal_store(o, out4 + j1);
    }
  }
}

// ---------------- KB: mean + contrast/saturation/hue, 4 px/thread (NT IO) ----------------
__global__ void kb_color(const __half* __restrict__ xh, const float* __restrict__ gpart,
                         const float* __restrict__ con, const float* __restrict__ sat,
                         const float* __restrict__ hue, float* __restrict__ xout,
                         int useHalf) {
  int tid = threadIdx.x, blk = blockIdx.x;
  int s = blk >> 6, slot = blk & 63;
  int u = slot*256 + tid;

  float sum = 0.f;
  for (int t = 0; t < 256; ++t) sum += gpart[s*256 + t];
  float mean = sum * (1.f / (float)OO_);
  float cf = con[s], sfc = sat[s], hu = hue[s];

  float in[3][4];
  #pragma unroll
  for (int ch = 0; ch < 3; ++ch) {
    size_t base = (size_t)(s*3 + ch)*OO_ + (size_t)u*4;
    if (useHalf) {
      u64 q = __builtin_nontemporal_load((const u64*)(xh + base));
      unsigned q0 = (unsigned)q, q1 = (unsigned)(q >> 32);
      __half2 h01 = *(__half2*)&q0;
      __half2 h23 = *(__half2*)&q1;
      float2 f01 = __half22float2(h01);
      float2 f23 = __half22float2(h23);
      in[ch][0]=f01.x; in[ch][1]=f01.y; in[ch][2]=f23.x; in[ch][3]=f23.y;
    } else {
      float4 f = ((const float4*)xout)[base >> 2];
      in[ch][0]=f.x; in[ch][1]=f.y; in[ch][2]=f.z; in[ch][3]=f.w;
    }
  }

  float ro[4], go[4], bo[4];
  #pragma unroll
  for (int l = 0; l < 4; ++l) {
    float r = in[0][l], g = in[1][l], bl = in[2][l];
    r  = clip01(cf*r  + (1.f-cf)*mean);
    g  = clip01(cf*g  + (1.f-cf)*mean);
    bl = clip01(cf*bl + (1.f-cf)*mean);

    float gr = 0.299f*r + 0.587f*g + 0.114f*bl;
    r  = clip01(sfc*r  + (1.f-sfc)*gr);
    g  = clip01(sfc*g  + (1.f-sfc)*gr);
    bl = clip01(sfc*bl + (1.f-sfc)*gr);

    const float eps = 1e-8f;
    float mx = fmaxf(r, fmaxf(g, bl));
    float mn = fminf(r, fminf(g, bl));
    float d  = mx - mn;
    float inv = 1.f / (d + eps);
    float h;
    if (mx == r)      h = pmodf_((g - bl) * inv, 6.f);
    else if (mx == g) h = (bl - r) * inv + 2.f;
    else              h = (r - g) * inv + 4.f;
    h *= (1.f/6.f);
    if (d <= eps) h = 0.f;
    float sv = d / (mx + eps);
    float v  = mx;

    h = pmodf_(h + hu, 1.f);

    float h6 = pmodf_(h, 1.f) * 6.f;
    float fi = floorf(h6);
    float f  = h6 - fi;
    int   i6 = ((int)fi) % 6;
    float pp = v * (1.f - sv);
    float q  = v * (1.f - f*sv);
    float t  = v * (1.f - (1.f - f)*sv);
    float rr, gg, bb;
    switch (i6) {
      case 0:  rr=v;  gg=t;  bb=pp; break;
      case 1:  rr=q;  gg=v;  bb=pp; break;
      case 2:  rr=pp; gg=v;  bb=t;  break;
      case 3:  rr=pp; gg=q;  bb=v;  break;
      case 4:  rr=t;  gg=pp; bb=v;  break;
      default: rr=v;  gg=pp; bb=q;  break;
    }
    ro[l] = clip01(rr); go[l] = clip01(gg); bo[l] = clip01(bb);
  }
  size_t ub = (size_t)(s*3)*OO_ + (size_t)u*4;
  fx4 vr = {ro[0],ro[1],ro[2],ro[3]};
  fx4 vg = {go[0],go[1],go[2],go[3]};
  fx4 vb = {bo[0],bo[1],bo[2],bo[3]};
  __builtin_nontemporal_store(vr, (fx4*)xout + ((ub)                 >> 2));
  __builtin_nontemporal_store(vg, (fx4*)xout + ((ub +   (size_t)OO_) >> 2));
  __builtin_nontemporal_store(vb, (fx4*)xout + ((ub + 2*(size_t)OO_) >> 2));
}

extern "C" void kernel_launch(void* const* d_in, const int* in_sizes, int n_in,
                              void* d_out, int out_size, void* d_ws, size_t ws_size,
                              hipStream_t stream) {
  const float* img = (const float*)d_in[0];
  const float* wc  = (const float*)d_in[1];
  const float* bm  = (const float*)d_in[2];
  const float* bg  = (const float*)d_in[3];
  const float* col = (const float*)d_in[4];
  const float* bri = (const float*)d_in[5];
  const float* con = (const float*)d_in[6];
  const float* sat = (const float*)d_in[7];
  const float* hue = (const float*)d_in[8];
  const int*   cb  = (const int*)d_in[9];

  float* outx  = (float*)d_out;
  float* outbm = outx + (size_t)B_*3*OO_;

  char* ws = (char*)d_ws;
  int*    pb    = (int*)ws;                                  // [0, 16384)
  float*  gpart = (float*)(ws + 16384);                      // 65536 B -> ends 81920
  Params* ptab  = (Params*)(ws + 81920);                     // 4096 B  -> ends 86016
  unsigned char* maskbits = (unsigned char*)(ws + 86016);    // 1,605,632 -> ends 1,691,648
  __half* xh = (__half*)(ws + 1691648);                      // 25,165,824 -> ends 26,857,472

  size_t needMask = 86016 + (size_t)B_*MBPS;
  size_t needHalf = 1691648 + (size_t)B_*3*OO_*2;
  int useMask = (ws_size >= needMask) ? 1 : 0;
  int useHalf = (ws_size >= needHalf) ? 1 : 0;

  k1_bboxmask<<<1024,  256, 0, stream>>>(wc, maskbits, pb, useMask);
  k0_params  <<<1,     64,  0, stream>>>(pb, cb, ptab);
  k2_compose <<<16384, 256, 0, stream>>>(img, bg, wc, maskbits, col, bri, ptab,
                                         bm, outbm, xh, outx, gpart,
                                         useMask, useHalf);
  kb_color   <<<4096,  256, 0, stream>>>(xh, gpart, con, sat, hue, outx, useHalf);
}